// Round 8
// baseline (2925.124 us; speedup 1.0000x reference)
//
#include <hip/hip_runtime.h>
#include <hip/hip_bf16.h>
#include <stdint.h>

#define BSZ 1024
#define HSZ 512
#define TSZ 48
#define INSZ 64
#define GSZ 2048  // 4*HSZ

typedef __attribute__((ext_vector_type(8))) short bf16x8;
typedef __attribute__((ext_vector_type(16))) float f32x16;

__device__ __forceinline__ float sigmf(float x) { return 1.0f / (1.0f + __expf(-x)); }
__device__ __forceinline__ float tanhf_(float x) { return 2.0f / (1.0f + __expf(-2.0f * x)) - 1.0f; }

// Layouts (bf16, hi/lo separate slabs):
//   A slabs (x per t, h per [par][layer]): [p=row/64][kc=hid/8][r=row&63][e=hid&7]
//   W slabs: [np=col'/128][kc=k/8][c=col'&127][e=k&7], col' = hidden*4+gate
// K-loop is LDS-FREE and BARRIER-FREE: A and B fragments are direct,
// perfectly-coalesced global loads (A reused 4x via L1 across waves; B reused
// 16x via per-XCD L2 across m-panel blocks thanks to the XCD swizzle).
// Software pipeline: ksub (K=16) granularity, 4 slots, hand-unrolled x4 so all
// slot indices are compile-time constants (no scratch spill).
// MFMA: 32x32x16 bf16, wave tile 64x32, 3-product hi/lo split.
// grid (16,16,ncells): 64 rows x 128 gate-cols per block, 256 threads.
__global__ __launch_bounds__(256, 3) void lstm_diag(
    const __hip_bfloat16* __restrict__ xth, const __hip_bfloat16* __restrict__ xtl,
    __hip_bfloat16* __restrict__ hbuf,   // [par][layer][hilo] pk-slabs
    float* __restrict__ Cbuf,            // [layer][B*H] linear f32
    const __hip_bfloat16* __restrict__ W0h, const __hip_bfloat16* __restrict__ W0l,
    const __hip_bfloat16* __restrict__ W1h, const __hip_bfloat16* __restrict__ W1l,
    const __hip_bfloat16* __restrict__ W2h, const __hip_bfloat16* __restrict__ W2l,
    const float* __restrict__ b0, const float* __restrict__ b1,
    const float* __restrict__ b2,
    int d, int lmin)
{
    __shared__ __align__(16) float gt[64 * 132];  // epilogue transpose only

    const int l = lmin + blockIdx.z;
    const int t = d - l;
    const size_t slab = (size_t)BSZ * HSZ;
    auto Hb = [&](int par, int ll, int hilo) {
        return hbuf + (((size_t)par * 3 + ll) * 2 + hilo) * slab;
    };

    const __hip_bfloat16* Wth = (l == 0) ? W0h : (l == 1) ? W1h : W2h;
    const __hip_bfloat16* Wtl = (l == 0) ? W0l : (l == 1) ? W1l : W2l;
    const float* bias = (l == 0) ? b0 : (l == 1) ? b1 : b2;
    const int Kx   = (l == 0) ? INSZ : HSZ;
    const int KCax = (l == 0) ? 8 : 64;   // kcs per panel in the x-source slab
    const int Ktot = Kx + HSZ;
    const int KCt  = Ktot >> 3;
    const int qx   = Kx >> 4;     // ksubs in x phase
    const int qtot = Ktot >> 4;   // total ksubs (36 or 64, both %4==0)
    const int cur = t & 1, prv = cur ^ 1;
    const __hip_bfloat16* Axh = (l == 0) ? xth + (size_t)t * BSZ * INSZ : Hb(cur, l - 1, 0);
    const __hip_bfloat16* Axl = (l == 0) ? xtl + (size_t)t * BSZ * INSZ : Hb(cur, l - 1, 1);
    const __hip_bfloat16* Ahh = Hb(prv, l, 0);
    const __hip_bfloat16* Ahl = Hb(prv, l, 1);
    float* C = Cbuf + (size_t)l * slab;
    __hip_bfloat16* hhi = Hb(cur, l, 0);
    __hip_bfloat16* hlo = Hb(cur, l, 1);

    // XCD-aware bijective swizzle within the 256-block z-slice (256 % 8 == 0).
    const int bid = blockIdx.x + (blockIdx.y << 4);
    const int swz = (bid & 7) * 32 + (bid >> 3);
    const int m0 = (swz & 15) * 64;
    const int n0 = (swz >> 4) * 128;
    const int p  = swz & 15;    // A row-panel
    const int np = swz >> 4;    // W col-panel

    const int tid = threadIdx.x;
    const int lane = tid & 63;
    const int wv = tid >> 6;
    const int lrow32 = lane & 31;
    const int lk2 = lane >> 5;

    // uniform byte bases
    const char* bAxh = (const char*)Axh + (size_t)p * KCax * 1024;
    const char* bAxl = (const char*)Axl + (size_t)p * KCax * 1024;
    const char* bAhh = (const char*)Ahh + (size_t)p * 64 * 1024;
    const char* bAhl = (const char*)Ahl + (size_t)p * 64 * 1024;
    const char* bWh  = (const char*)Wth + (size_t)np * KCt * 2048;
    const char* bWl  = (const char*)Wtl + (size_t)np * KCt * 2048;

    // per-lane byte offsets within a kc-pair
    const int aoff = lk2 * 1024 + lrow32 * 16;                 // + mf*512
    const int boff = lk2 * 2048 + (wv * 32 + lrow32) * 16;

    f32x16 acc0, acc1;
#pragma unroll
    for (int r = 0; r < 16; ++r) { acc0[r] = 0.0f; acc1[r] = 0.0f; }

    bf16x8 ah[4][2], al[4][2], bhv[4], blv[4];

#define LOAD_SLOT(S, Q)                                                       \
    { const int q_ = (Q);                                                     \
      const char *pah, *pal;                                                  \
      if (q_ < qx) { pah = bAxh + q_ * 2048; pal = bAxl + q_ * 2048; }        \
      else { pah = bAhh + (q_ - qx) * 2048; pal = bAhl + (q_ - qx) * 2048; }  \
      ah[S][0] = *(const bf16x8*)(pah + aoff);                                \
      ah[S][1] = *(const bf16x8*)(pah + aoff + 512);                          \
      al[S][0] = *(const bf16x8*)(pal + aoff);                                \
      al[S][1] = *(const bf16x8*)(pal + aoff + 512);                          \
      bhv[S] = __builtin_nontemporal_load((const bf16x8*)(bWh + q_ * 4096 + boff)); \
      blv[S] = __builtin_nontemporal_load((const bf16x8*)(bWl + q_ * 4096 + boff)); }

#define MMA_SLOT(S)                                                           \
    acc0 = __builtin_amdgcn_mfma_f32_32x32x16_bf16(ah[S][0], bhv[S], acc0, 0, 0, 0); \
    acc1 = __builtin_amdgcn_mfma_f32_32x32x16_bf16(ah[S][1], bhv[S], acc1, 0, 0, 0); \
    acc0 = __builtin_amdgcn_mfma_f32_32x32x16_bf16(al[S][0], bhv[S], acc0, 0, 0, 0); \
    acc1 = __builtin_amdgcn_mfma_f32_32x32x16_bf16(al[S][1], bhv[S], acc1, 0, 0, 0); \
    acc0 = __builtin_amdgcn_mfma_f32_32x32x16_bf16(ah[S][0], blv[S], acc0, 0, 0, 0); \
    acc1 = __builtin_amdgcn_mfma_f32_32x32x16_bf16(ah[S][1], blv[S], acc1, 0, 0, 0);

    LOAD_SLOT(0, 0)
    LOAD_SLOT(1, 1)
    LOAD_SLOT(2, 2)
    LOAD_SLOT(3, 3)

#pragma unroll 1
    for (int qq = 0; qq < qtot; qq += 4) {
        MMA_SLOT(0) if (qq + 4 < qtot) LOAD_SLOT(0, qq + 4)
        MMA_SLOT(1) if (qq + 5 < qtot) LOAD_SLOT(1, qq + 5)
        MMA_SLOT(2) if (qq + 6 < qtot) LOAD_SLOT(2, qq + 6)
        MMA_SLOT(3) if (qq + 7 < qtot) LOAD_SLOT(3, qq + 7)
    }
#undef LOAD_SLOT
#undef MMA_SLOT

    // ---- epilogue: acc -> LDS [64][132] f32, then fused cell update ----
    __syncthreads();
#pragma unroll
    for (int rg = 0; rg < 16; ++rg) {
        int row0 = (rg & 3) + 8 * (rg >> 2) + 4 * lk2;
        gt[row0 * 132 + wv * 32 + lrow32] = acc0[rg];
        gt[(row0 + 32) * 132 + wv * 32 + lrow32] = acc1[rg];
    }
    __syncthreads();

    const int n_l = tid & 31;
    const int rb2 = (tid >> 5) * 8;
    const int n_g = (n0 >> 2) + n_l;  // global hidden unit
    const int kc_h = n_g >> 3, e_h = n_g & 7;
    const float bf = bias[n_g], bi = bias[HSZ + n_g];
    const float bc = bias[2 * HSZ + n_g], bo = bias[3 * HSZ + n_g];
#pragma unroll
    for (int r = 0; r < 8; ++r) {
        int row = rb2 + r;
        int rg = m0 + row;
        float4 g4 = *(const float4*)&gt[row * 132 + n_l * 4];  // f,i,c,o
        float f = sigmf(g4.x + bf);
        float i_ = sigmf(g4.y + bi);
        float c_ = tanhf_(g4.z + bc);
        float o_ = sigmf(g4.w + bo);
        size_t cidx = (size_t)rg * HSZ + n_g;
        float Cn = f * C[cidx] + i_ * c_;
        C[cidx] = Cn;
        float hv = o_ * tanhf_(Cn);
        __hip_bfloat16 hh = __float2bfloat16(hv);
        size_t hidx = (((size_t)(rg >> 6) * 64 + kc_h) * 64 + (rg & 63)) * 8 + e_h;
        hhi[hidx] = hh;
        hlo[hidx] = __float2bfloat16(hv - __bfloat162float(hh));
    }
}

// x[B][T][64] f32 -> xt_pk[t][p][kc][r][e] bf16 hi/lo
__global__ __launch_bounds__(256) void convert_x(const float* __restrict__ x,
                                                 __hip_bfloat16* __restrict__ xh,
                                                 __hip_bfloat16* __restrict__ xl)
{
    int gid = blockIdx.x * 256 + threadIdx.x;  // T*16*64*8
    int kc = gid & 7;
    int rem = gid >> 3;
    int r = rem & 63; rem >>= 6;
    int pp = rem & 15;
    int t = rem >> 4;
    int b = pp * 64 + r;
    const float* src = x + ((size_t)b * TSZ + t) * INSZ + kc * 8;
    short hi8[8], lo8[8];
#pragma unroll
    for (int e = 0; e < 8; ++e) {
        float v = src[e];
        __hip_bfloat16 h = __float2bfloat16(v);
        hi8[e] = *(short*)&h;
        __hip_bfloat16 lo = __float2bfloat16(v - __bfloat162float(h));
        lo8[e] = *(short*)&lo;
    }
    size_t o = ((((size_t)t * 16 + pp) * 8 + kc) * 64 + r) * 8;
    *(bf16x8*)((__hip_bfloat16*)xh + o) = *(bf16x8*)hi8;
    *(bf16x8*)((__hip_bfloat16*)xl + o) = *(bf16x8*)lo8;
}

// W[k][gate*512+n] f32 (Wx then Wh stacked in k) -> W_pk[np][kc][c][e] bf16 hi/lo
// grid (Ktot/64, 16): block = (kt, np), 64 k x 128 col'
__global__ __launch_bounds__(256) void convert_w(
    const float* __restrict__ Wx, const float* __restrict__ Wh, int Kx, int Ktot,
    __hip_bfloat16* __restrict__ outh, __hip_bfloat16* __restrict__ outl)
{
    __shared__ float tile[64][129];
    const int kt = blockIdx.x, np = blockIdx.y;
    const int k0 = kt * 64;
    const float* src;
    int krel;
    if (k0 < Kx) { src = Wx; krel = k0; } else { src = Wh; krel = k0 - Kx; }
#pragma unroll
    for (int i = 0; i < 32; ++i) {
        int idx = threadIdx.x + i * 256;
        int k_l = idx >> 7, gate = (idx >> 5) & 3, n_l = idx & 31;
        tile[k_l][n_l * 4 + gate] = src[(size_t)(krel + k_l) * GSZ + gate * HSZ + np * 32 + n_l];
    }
    __syncthreads();
    const size_t obase = ((size_t)np * (Ktot >> 3) + kt * 8) * 1024;
#pragma unroll
    for (int i = 0; i < 32; ++i) {
        int idx = threadIdx.x + i * 256;
        int kcl = idx >> 10, c = (idx >> 3) & 127, e = idx & 7;
        float v = tile[kcl * 8 + e][c];
        __hip_bfloat16 h = __float2bfloat16(v);
        outh[obase + idx] = h;
        outl[obase + idx] = __float2bfloat16(v - __bfloat162float(h));
    }
}

// out[b] = sum_n (hh+hl)[b][n]*w[n] + bias, h in pk layout
__global__ __launch_bounds__(256) void fc_kernel(
    const __hip_bfloat16* __restrict__ hh, const __hip_bfloat16* __restrict__ hl,
    const float* __restrict__ w, const float* __restrict__ b, float* __restrict__ out)
{
    int wave = (blockIdx.x * 256 + threadIdx.x) >> 6;  // batch row
    int lane = threadIdx.x & 63;
    if (wave >= BSZ) return;
    int pp = wave >> 6, r = wave & 63;
    size_t o = (((size_t)pp * 64 + lane) * 64 + r) * 8;  // kc = lane
    bf16x8 vh = *(const bf16x8*)(hh + o);
    bf16x8 vl = *(const bf16x8*)(hl + o);
    float s = 0.0f;
#pragma unroll
    for (int e = 0; e < 8; ++e) {
        ushort uh = (ushort)vh[e], ul = (ushort)vl[e];
        __hip_bfloat16 bh = *(__hip_bfloat16*)&uh;
        __hip_bfloat16 bl = *(__hip_bfloat16*)&ul;
        s += (__bfloat162float(bh) + __bfloat162float(bl)) * w[lane * 8 + e];
    }
#pragma unroll
    for (int off = 32; off; off >>= 1) s += __shfl_down(s, off);
    if (lane == 0) out[wave] = s + b[0];
}

extern "C" void kernel_launch(void* const* d_in, const int* in_sizes, int n_in,
                              void* d_out, int out_size, void* d_ws, size_t ws_size,
                              hipStream_t stream) {
    const float* x   = (const float*)d_in[0];
    const float* Wx0 = (const float*)d_in[1];
    const float* Wh0 = (const float*)d_in[2];
    const float* b0  = (const float*)d_in[3];
    const float* Wx1 = (const float*)d_in[4];
    const float* Wh1 = (const float*)d_in[5];
    const float* b1  = (const float*)d_in[6];
    const float* Wx2 = (const float*)d_in[7];
    const float* Wh2 = (const float*)d_in[8];
    const float* b2  = (const float*)d_in[9];
    const float* fcw = (const float*)d_in[10];
    const float* fcb = (const float*)d_in[11];

    char* p = (char*)d_ws;
    const size_t hslab = (size_t)BSZ * HSZ * sizeof(__hip_bfloat16);  // 1 MiB
    __hip_bfloat16* hbuf = (__hip_bfloat16*)p;  // [par][layer][hi/lo] 12 slabs
    p += 12 * hslab;
    float* Cbuf = (float*)p;  // [3][B][H] f32
    p += 3 * (size_t)BSZ * HSZ * sizeof(float);
    const size_t zero_bytes = (size_t)(p - (char*)d_ws);

    const size_t xslab = (size_t)TSZ * BSZ * INSZ * sizeof(__hip_bfloat16);
    __hip_bfloat16* xth = (__hip_bfloat16*)p; p += xslab;
    __hip_bfloat16* xtl = (__hip_bfloat16*)p; p += xslab;

    const int K0 = INSZ + HSZ;   // 576
    const int K12 = 2 * HSZ;     // 1024
    const size_t w0s = (size_t)GSZ * K0 * sizeof(__hip_bfloat16);
    const size_t w12s = (size_t)GSZ * K12 * sizeof(__hip_bfloat16);
    __hip_bfloat16* w0h = (__hip_bfloat16*)p; p += w0s;
    __hip_bfloat16* w0l = (__hip_bfloat16*)p; p += w0s;
    __hip_bfloat16* w1h = (__hip_bfloat16*)p; p += w12s;
    __hip_bfloat16* w1l = (__hip_bfloat16*)p; p += w12s;
    __hip_bfloat16* w2h = (__hip_bfloat16*)p; p += w12s;
    __hip_bfloat16* w2l = (__hip_bfloat16*)p; p += w12s;

    hipMemsetAsync(d_ws, 0, zero_bytes, stream);

    convert_x<<<dim3(TSZ * BSZ * 8 / 256), dim3(256), 0, stream>>>(x, xth, xtl);
    convert_w<<<dim3(K0 / 64, 16), dim3(256), 0, stream>>>(Wx0, Wh0, INSZ, K0, w0h, w0l);
    convert_w<<<dim3(K12 / 64, 16), dim3(256), 0, stream>>>(Wx1, Wh1, HSZ, K12, w1h, w1l);
    convert_w<<<dim3(K12 / 64, 16), dim3(256), 0, stream>>>(Wx2, Wh2, HSZ, K12, w2h, w2l);

    // diagonal wavefront: d = t + l, cells (t,l) with t+l == d are independent
    for (int dgn = 0; dgn < TSZ + 2; ++dgn) {
        int lmin = (dgn - (TSZ - 1)) > 0 ? (dgn - (TSZ - 1)) : 0;
        int lmax = dgn < 2 ? dgn : 2;
        int ncells = lmax - lmin + 1;
        lstm_diag<<<dim3(16, 16, ncells), dim3(256), 0, stream>>>(
            xth, xtl, hbuf, Cbuf,
            w0h, w0l, w1h, w1l, w2h, w2l,
            b0, b1, b2, dgn, lmin);
    }

    // h of layer 2 at t=47 lives at parity 47&1 = 1
    __hip_bfloat16* h2h = hbuf + (((size_t)1 * 3 + 2) * 2 + 0) * BSZ * HSZ;
    __hip_bfloat16* h2l = hbuf + (((size_t)1 * 3 + 2) * 2 + 1) * BSZ * HSZ;
    fc_kernel<<<dim3(BSZ / 4), dim3(256), 0, stream>>>(h2h, h2l, fcw, fcb, (float*)d_out);
}

// Round 10
// 2225.626 us; speedup vs baseline: 1.3143x; 1.3143x over previous
//
#include <hip/hip_runtime.h>
#include <hip/hip_bf16.h>
#include <stdint.h>

#define BSZ 1024
#define HSZ 512
#define TSZ 48
#define INSZ 64
#define GSZ 2048  // 4*HSZ

typedef __attribute__((ext_vector_type(8))) short bf16x8;
typedef __attribute__((ext_vector_type(16))) float f32x16;

#define GLDS16(g, l)                                                        \
    __builtin_amdgcn_global_load_lds(                                       \
        (const __attribute__((address_space(1))) void*)(g),                 \
        (__attribute__((address_space(3))) void*)(l), 16, 0, 0)

__device__ __forceinline__ float sigmf(float x) { return 1.0f / (1.0f + __expf(-x)); }
__device__ __forceinline__ float tanhf_(float x) { return 2.0f / (1.0f + __expf(-2.0f * x)) - 1.0f; }

// Layouts (bf16, hi/lo separate slabs):
//   A slabs (x per t, h per [par][layer]): [p=row/64][kc=hid/8][r=row&63][e=hid&7]
//   W slabs: [np=col'/128][kc=k/8][c=col'&127][e=k&7], col' = hidden*4+gate
// Hybrid staging (r5 was LDS-BW-bound at 144KB/block-kstep; r8 was HBM-bound):
//   A -> LDS via global_load_lds, double-buffered, T3 2-phase shape
//        (barrier at top of iter; stage(ks+1) issued after this iter's B loads)
//   B -> direct global->VGPR (plain loads, L2-resident via XCD swizzle).
//   B loads issued FIRST, then stage glds (sched_barrier-pinned), so B-consume
//   waits vmcnt(4) and never drains the A prefetch (the r6 bug).
// Wave tile 32x64 (2 n-frags of 32x32): per-wave A LDS read = 8KB/kstep.
// LDS per block-kstep: 16KB write + 32KB read = 48KB (vs r5's 144KB).
// MFMA: 32x32x16 bf16, 3-product hi/lo split (hi*hi + lo*hi + hi*lo).
// grid (16,16,ncells): 64 rows x 128 gate-cols per block, 256 threads.
__global__ __launch_bounds__(256, 3) void lstm_diag(
    const __hip_bfloat16* __restrict__ xth, const __hip_bfloat16* __restrict__ xtl,
    __hip_bfloat16* __restrict__ hbuf,   // [par][layer][hilo] pk-slabs
    float* __restrict__ Cbuf,            // [layer][B*H] linear f32
    const __hip_bfloat16* __restrict__ W0h, const __hip_bfloat16* __restrict__ W0l,
    const __hip_bfloat16* __restrict__ W1h, const __hip_bfloat16* __restrict__ W1l,
    const __hip_bfloat16* __restrict__ W2h, const __hip_bfloat16* __restrict__ W2l,
    const float* __restrict__ b0, const float* __restrict__ b1,
    const float* __restrict__ b2,
    int d, int lmin)
{
    // A dbuf: 2 x (hi 8K | lo 8K) = 32K; epilogue gt 64*132*4 = 33792 (aliased)
    __shared__ __align__(16) char lds[33792];

    const int l = lmin + blockIdx.z;
    const int t = d - l;
    const size_t slab = (size_t)BSZ * HSZ;
    auto Hb = [&](int par, int ll, int hilo) {
        return hbuf + (((size_t)par * 3 + ll) * 2 + hilo) * slab;
    };

    const __hip_bfloat16* Wth = (l == 0) ? W0h : (l == 1) ? W1h : W2h;
    const __hip_bfloat16* Wtl = (l == 0) ? W0l : (l == 1) ? W1l : W2l;
    const float* bias = (l == 0) ? b0 : (l == 1) ? b1 : b2;
    const int Kx   = (l == 0) ? INSZ : HSZ;
    const int KCax = (l == 0) ? 8 : 64;   // kcs per panel in the x-source slab
    const int Ktot = Kx + HSZ;
    const int KCt  = Ktot >> 3;
    const int nkx  = Kx >> 6;     // ksteps in x phase (1 or 8)
    const int nkt  = Ktot >> 6;   // total ksteps (9 or 16)
    const int cur = t & 1, prv = cur ^ 1;
    const __hip_bfloat16* Axh = (l == 0) ? xth + (size_t)t * BSZ * INSZ : Hb(cur, l - 1, 0);
    const __hip_bfloat16* Axl = (l == 0) ? xtl + (size_t)t * BSZ * INSZ : Hb(cur, l - 1, 1);
    const __hip_bfloat16* Ahh = Hb(prv, l, 0);
    const __hip_bfloat16* Ahl = Hb(prv, l, 1);
    float* C = Cbuf + (size_t)l * slab;
    __hip_bfloat16* hhi = Hb(cur, l, 0);
    __hip_bfloat16* hlo = Hb(cur, l, 1);

    // XCD-aware bijective swizzle within the 256-block z-slice (256 % 8 == 0).
    const int bid = blockIdx.x + (blockIdx.y << 4);
    const int swz = (bid & 7) * 32 + (bid >> 3);
    const int m0 = (swz & 15) * 64;
    const int n0 = (swz >> 4) * 128;
    const int p  = swz & 15;    // A row-panel
    const int np = swz >> 4;    // W col-panel

    const int tid = threadIdx.x;
    const int lane = tid & 63;
    const int wv = tid >> 6;
    const int lrow32 = lane & 31;
    const int lk2 = lane >> 5;

    // wave tile: rows r0..r0+31, cols c0w..c0w+63 (2 n-frags of 32)
    const int r0  = (wv >> 1) * 32;
    const int c0w = (wv & 1) * 64;

    // A source byte bases (panel-resolved)
    const char* bAxh = (const char*)Axh + (size_t)p * KCax * 1024;
    const char* bAxl = (const char*)Axl + (size_t)p * KCax * 1024;
    const char* bAhh = (const char*)Ahh + (size_t)p * 64 * 1024;
    const char* bAhl = (const char*)Ahl + (size_t)p * 64 * 1024;
    // W byte bases (panel-resolved)
    const char* bWh = (const char*)Wth + (size_t)np * KCt * 2048;
    const char* bWl = (const char*)Wtl + (size_t)np * KCt * 2048;

    // per-lane offsets
    const int aoff = (r0 + lrow32) * 16;                // A ds_read, + kc*1024
    const int boff = (c0w + lrow32) * 16;               // B global, + nf*512 + kc*2048

    f32x16 acc0, acc1;
#pragma unroll
    for (int r = 0; r < 16; ++r) { acc0[r] = 0.0f; acc1[r] = 0.0f; }

    // stage A kstep ks into buf[ks&1]: 16 x 1KB segments, 4 per wave
    auto stage = [&](int ks) {
        const char *sh, *sl;
        int kc0;
        if (ks < nkx) { sh = bAxh; sl = bAxl; kc0 = ks * 8; }
        else          { sh = bAhh; sl = bAhl; kc0 = (ks - nkx) * 8; }
        char* dst = lds + (ks & 1) * 16384;
#pragma unroll
        for (int i = 0; i < 2; ++i) {
            int kc = wv * 2 + i;
            size_t so = (size_t)(kc0 + kc) * 1024 + lane * 16;
            GLDS16(sh + so, dst + kc * 1024);
            GLDS16(sl + so, dst + 8192 + kc * 1024);
        }
    };

    stage(0);

#pragma unroll 1
    for (int ks = 0; ks < nkt; ++ks) {
        // top-of-iter barrier: implicit vmcnt(0) drains stage(ks) (issued a
        // full compute ago) and syncs WAR for buf[(ks+1)&1].
        __syncthreads();

        // B register loads FIRST (consumed this kstep)
        bf16x8 bh[4][2], bl[4][2];
        {
            const char* wb = bWh + (size_t)ks * 16384;
            const char* wl = bWl + (size_t)ks * 16384;
#pragma unroll
            for (int s = 0; s < 4; ++s) {
                int ko = (s * 2 + lk2) * 2048;
                bh[s][0] = *(const bf16x8*)(wb + ko + boff);
                bh[s][1] = *(const bf16x8*)(wb + ko + boff + 512);
                bl[s][0] = *(const bf16x8*)(wl + ko + boff);
                bl[s][1] = *(const bf16x8*)(wl + ko + boff + 512);
            }
        }
        __builtin_amdgcn_sched_barrier(0);  // keep stage glds AFTER B loads

        if (ks + 1 < nkt) stage(ks + 1);    // prefetch next A tile (4 glds)
        __builtin_amdgcn_sched_barrier(0);

        // compute on buf[ks&1]; B-consume waits vmcnt(4) (stage in flight)
        char* bufb = lds + (ks & 1) * 16384;
        __builtin_amdgcn_s_setprio(1);
#pragma unroll
        for (int s = 0; s < 4; ++s) {
            int ao = (s * 2 + lk2) * 1024 + aoff;
            bf16x8 ahv = *(const bf16x8*)(bufb + ao);
            bf16x8 alv = *(const bf16x8*)(bufb + 8192 + ao);
            acc0 = __builtin_amdgcn_mfma_f32_32x32x16_bf16(ahv, bh[s][0], acc0, 0, 0, 0);
            acc1 = __builtin_amdgcn_mfma_f32_32x32x16_bf16(ahv, bh[s][1], acc1, 0, 0, 0);
            acc0 = __builtin_amdgcn_mfma_f32_32x32x16_bf16(alv, bh[s][0], acc0, 0, 0, 0);
            acc1 = __builtin_amdgcn_mfma_f32_32x32x16_bf16(alv, bh[s][1], acc1, 0, 0, 0);
            acc0 = __builtin_amdgcn_mfma_f32_32x32x16_bf16(ahv, bl[s][0], acc0, 0, 0, 0);
            acc1 = __builtin_amdgcn_mfma_f32_32x32x16_bf16(ahv, bl[s][1], acc1, 0, 0, 0);
        }
        __builtin_amdgcn_s_setprio(0);
    }

    // ---- epilogue: acc -> LDS [64][132] f32, then fused cell update ----
    __syncthreads();  // all waves done reading A bufs (gt aliases them)
    float* gt = (float*)lds;
#pragma unroll
    for (int rg = 0; rg < 16; ++rg) {
        int row = r0 + (rg & 3) + 8 * (rg >> 2) + 4 * lk2;
        gt[row * 132 + c0w + lrow32] = acc0[rg];
        gt[row * 132 + c0w + 32 + lrow32] = acc1[rg];
    }
    __syncthreads();

    const int n_l = tid & 31;
    const int rb2 = (tid >> 5) * 8;
    const int n_g = (n0 >> 2) + n_l;  // global hidden unit
    const int kc_h = n_g >> 3, e_h = n_g & 7;
    const float bf = bias[n_g], bi = bias[HSZ + n_g];
    const float bc = bias[2 * HSZ + n_g], bo = bias[3 * HSZ + n_g];
#pragma unroll
    for (int r = 0; r < 8; ++r) {
        int row = rb2 + r;
        int rg = m0 + row;
        float4 g4 = *(const float4*)&gt[row * 132 + n_l * 4];  // f,i,c,o
        float f = sigmf(g4.x + bf);
        float i_ = sigmf(g4.y + bi);
        float c_ = tanhf_(g4.z + bc);
        float o_ = sigmf(g4.w + bo);
        size_t cidx = (size_t)rg * HSZ + n_g;
        float Cn = f * C[cidx] + i_ * c_;
        C[cidx] = Cn;
        float hv = o_ * tanhf_(Cn);
        __hip_bfloat16 hh = __float2bfloat16(hv);
        size_t hidx = (((size_t)(rg >> 6) * 64 + kc_h) * 64 + (rg & 63)) * 8 + e_h;
        hhi[hidx] = hh;
        hlo[hidx] = __float2bfloat16(hv - __bfloat162float(hh));
    }
}

// x[B][T][64] f32 -> xt_pk[t][p][kc][r][e] bf16 hi/lo
__global__ __launch_bounds__(256) void convert_x(const float* __restrict__ x,
                                                 __hip_bfloat16* __restrict__ xh,
                                                 __hip_bfloat16* __restrict__ xl)
{
    int gid = blockIdx.x * 256 + threadIdx.x;  // T*16*64*8
    int kc = gid & 7;
    int rem = gid >> 3;
    int r = rem & 63; rem >>= 6;
    int pp = rem & 15;
    int t = rem >> 4;
    int b = pp * 64 + r;
    const float* src = x + ((size_t)b * TSZ + t) * INSZ + kc * 8;
    short hi8[8], lo8[8];
#pragma unroll
    for (int e = 0; e < 8; ++e) {
        float v = src[e];
        __hip_bfloat16 h = __float2bfloat16(v);
        hi8[e] = *(short*)&h;
        __hip_bfloat16 lo = __float2bfloat16(v - __bfloat162float(h));
        lo8[e] = *(short*)&lo;
    }
    size_t o = ((((size_t)t * 16 + pp) * 8 + kc) * 64 + r) * 8;
    *(bf16x8*)((__hip_bfloat16*)xh + o) = *(bf16x8*)hi8;
    *(bf16x8*)((__hip_bfloat16*)xl + o) = *(bf16x8*)lo8;
}

// W[k][gate*512+n] f32 (Wx then Wh stacked in k) -> W_pk[np][kc][c][e] bf16 hi/lo
// grid (Ktot/64, 16): block = (kt, np), 64 k x 128 col'
__global__ __launch_bounds__(256) void convert_w(
    const float* __restrict__ Wx, const float* __restrict__ Wh, int Kx, int Ktot,
    __hip_bfloat16* __restrict__ outh, __hip_bfloat16* __restrict__ outl)
{
    __shared__ float tile[64][129];
    const int kt = blockIdx.x, np = blockIdx.y;
    const int k0 = kt * 64;
    const float* src;
    int krel;
    if (k0 < Kx) { src = Wx; krel = k0; } else { src = Wh; krel = k0 - Kx; }
#pragma unroll
    for (int i = 0; i < 32; ++i) {
        int idx = threadIdx.x + i * 256;
        int k_l = idx >> 7, gate = (idx >> 5) & 3, n_l = idx & 31;
        tile[k_l][n_l * 4 + gate] = src[(size_t)(krel + k_l) * GSZ + gate * HSZ + np * 32 + n_l];
    }
    __syncthreads();
    const size_t obase = ((size_t)np * (Ktot >> 3) + kt * 8) * 1024;
#pragma unroll
    for (int i = 0; i < 32; ++i) {
        int idx = threadIdx.x + i * 256;
        int kcl = idx >> 10, c = (idx >> 3) & 127, e = idx & 7;
        float v = tile[kcl * 8 + e][c];
        __hip_bfloat16 h = __float2bfloat16(v);
        outh[obase + idx] = h;
        outl[obase + idx] = __float2bfloat16(v - __bfloat162float(h));
    }
}

// out[b] = sum_n (hh+hl)[b][n]*w[n] + bias, h in pk layout
__global__ __launch_bounds__(256) void fc_kernel(
    const __hip_bfloat16* __restrict__ hh, const __hip_bfloat16* __restrict__ hl,
    const float* __restrict__ w, const float* __restrict__ b, float* __restrict__ out)
{
    int wave = (blockIdx.x * 256 + threadIdx.x) >> 6;  // batch row
    int lane = threadIdx.x & 63;
    if (wave >= BSZ) return;
    int pp = wave >> 6, r = wave & 63;
    size_t o = (((size_t)pp * 64 + lane) * 64 + r) * 8;  // kc = lane
    bf16x8 vh = *(const bf16x8*)(hh + o);
    bf16x8 vl = *(const bf16x8*)(hl + o);
    float s = 0.0f;
#pragma unroll
    for (int e = 0; e < 8; ++e) {
        ushort uh = (ushort)vh[e], ul = (ushort)vl[e];
        __hip_bfloat16 bh = *(__hip_bfloat16*)&uh;
        __hip_bfloat16 bl = *(__hip_bfloat16*)&ul;
        s += (__bfloat162float(bh) + __bfloat162float(bl)) * w[lane * 8 + e];
    }
#pragma unroll
    for (int off = 32; off; off >>= 1) s += __shfl_down(s, off);
    if (lane == 0) out[wave] = s + b[0];
}

extern "C" void kernel_launch(void* const* d_in, const int* in_sizes, int n_in,
                              void* d_out, int out_size, void* d_ws, size_t ws_size,
                              hipStream_t stream) {
    const float* x   = (const float*)d_in[0];
    const float* Wx0 = (const float*)d_in[1];
    const float* Wh0 = (const float*)d_in[2];
    const float* b0  = (const float*)d_in[3];
    const float* Wx1 = (const float*)d_in[4];
    const float* Wh1 = (const float*)d_in[5];
    const float* b1  = (const float*)d_in[6];
    const float* Wx2 = (const float*)d_in[7];
    const float* Wh2 = (const float*)d_in[8];
    const float* b2  = (const float*)d_in[9];
    const float* fcw = (const float*)d_in[10];
    const float* fcb = (const float*)d_in[11];

    char* p = (char*)d_ws;
    const size_t hslab = (size_t)BSZ * HSZ * sizeof(__hip_bfloat16);  // 1 MiB
    __hip_bfloat16* hbuf = (__hip_bfloat16*)p;  // [par][layer][hi/lo] 12 slabs
    p += 12 * hslab;
    float* Cbuf = (float*)p;  // [3][B][H] f32
    p += 3 * (size_t)BSZ * HSZ * sizeof(float);
    const size_t zero_bytes = (size_t)(p - (char*)d_ws);

    const size_t xslab = (size_t)TSZ * BSZ * INSZ * sizeof(__hip_bfloat16);
    __hip_bfloat16* xth = (__hip_bfloat16*)p; p += xslab;
    __hip_bfloat16* xtl = (__hip_bfloat16*)p; p += xslab;

    const int K0 = INSZ + HSZ;   // 576
    const int K12 = 2 * HSZ;     // 1024
    const size_t w0s = (size_t)GSZ * K0 * sizeof(__hip_bfloat16);
    const size_t w12s = (size_t)GSZ * K12 * sizeof(__hip_bfloat16);
    __hip_bfloat16* w0h = (__hip_bfloat16*)p; p += w0s;
    __hip_bfloat16* w0l = (__hip_bfloat16*)p; p += w0s;
    __hip_bfloat16* w1h = (__hip_bfloat16*)p; p += w12s;
    __hip_bfloat16* w1l = (__hip_bfloat16*)p; p += w12s;
    __hip_bfloat16* w2h = (__hip_bfloat16*)p; p += w12s;
    __hip_bfloat16* w2l = (__hip_bfloat16*)p; p += w12s;

    hipMemsetAsync(d_ws, 0, zero_bytes, stream);

    convert_x<<<dim3(TSZ * BSZ * 8 / 256), dim3(256), 0, stream>>>(x, xth, xtl);
    convert_w<<<dim3(K0 / 64, 16), dim3(256), 0, stream>>>(Wx0, Wh0, INSZ, K0, w0h, w0l);
    convert_w<<<dim3(K12 / 64, 16), dim3(256), 0, stream>>>(Wx1, Wh1, HSZ, K12, w1h, w1l);
    convert_w<<<dim3(K12 / 64, 16), dim3(256), 0, stream>>>(Wx2, Wh2, HSZ, K12, w2h, w2l);

    // diagonal wavefront: d = t + l, cells (t,l) with t+l == d are independent
    for (int dgn = 0; dgn < TSZ + 2; ++dgn) {
        int lmin = (dgn - (TSZ - 1)) > 0 ? (dgn - (TSZ - 1)) : 0;
        int lmax = dgn < 2 ? dgn : 2;
        int ncells = lmax - lmin + 1;
        lstm_diag<<<dim3(16, 16, ncells), dim3(256), 0, stream>>>(
            xth, xtl, hbuf, Cbuf,
            w0h, w0l, w1h, w1l, w2h, w2l,
            b0, b1, b2, dgn, lmin);
    }

    // h of layer 2 at t=47 lives at parity 47&1 = 1
    __hip_bfloat16* h2h = hbuf + (((size_t)1 * 3 + 2) * 2 + 0) * BSZ * HSZ;
    __hip_bfloat16* h2l = hbuf + (((size_t)1 * 3 + 2) * 2 + 1) * BSZ * HSZ;
    fc_kernel<<<dim3(BSZ / 4), dim3(256), 0, stream>>>(h2h, h2l, fcw, fcb, (float*)d_out);
}

// Round 11
// 1964.239 us; speedup vs baseline: 1.4892x; 1.1331x over previous
//
#include <hip/hip_runtime.h>
#include <hip/hip_bf16.h>
#include <stdint.h>

#define BSZ 1024
#define HSZ 512
#define TSZ 48
#define INSZ 64
#define GSZ 2048  // 4*HSZ

typedef __attribute__((ext_vector_type(8))) short bf16x8;
typedef __attribute__((ext_vector_type(16))) float f32x16;

#define GLDS16(g, l)                                                        \
    __builtin_amdgcn_global_load_lds(                                       \
        (const __attribute__((address_space(1))) void*)(g),                 \
        (__attribute__((address_space(3))) void*)(l), 16, 0, 0)

__device__ __forceinline__ float sigmf(float x) { return 1.0f / (1.0f + __expf(-x)); }
__device__ __forceinline__ float tanhf_(float x) { return 2.0f / (1.0f + __expf(-2.0f * x)) - 1.0f; }

// Layouts (bf16, hi/lo separate slabs):
//   A slabs: [p=row/64][kc=hid/8][r=row&63][e=hid&7]
//   W slabs: [np=col'/128][kc=k/8][c=col'&127][e=k&7], col' = hidden*4+gate
// r10 diagnosis: B direct-loads are L3-latency (~600-900cy, W evicted from L2
// by streamed A/C/h) and were consumed in-kstep -> ~50% stall.
// Fix: B REGISTER DOUBLE-BUFFER -- load B[ks+1] into the alternate named set
// (bA/bB, even/odd unrolled; rule #20) while computing with B[ks]. Compute has
// ZERO vmcnt waits; the barrier's vmcnt(0) drain lands a full compute after
// issue. A stays in dbuf LDS via global_load_lds (4x cross-wave reuse).
// Wave tile 64x32 (2 m-frags x 1 n-frag): B footprint 8 regs/set.
// MFMA: 32x32x16 bf16, 3-product hi/lo split (hi*hi + lo*hi + hi*lo).
// grid (16,16,ncells): 64 rows x 128 gate-cols per block, 256 threads.
__global__ __launch_bounds__(256, 3) void lstm_diag(
    const __hip_bfloat16* __restrict__ xth, const __hip_bfloat16* __restrict__ xtl,
    __hip_bfloat16* __restrict__ hbuf,   // [par][layer][hilo] pk-slabs
    float* __restrict__ Cbuf,            // [layer][B*H] linear f32
    const __hip_bfloat16* __restrict__ W0h, const __hip_bfloat16* __restrict__ W0l,
    const __hip_bfloat16* __restrict__ W1h, const __hip_bfloat16* __restrict__ W1l,
    const __hip_bfloat16* __restrict__ W2h, const __hip_bfloat16* __restrict__ W2l,
    const float* __restrict__ b0, const float* __restrict__ b1,
    const float* __restrict__ b2,
    int d, int lmin)
{
    // A dbuf: 2 x (hi 8K | lo 8K) = 32K; epilogue gt 64*132*4 = 33792 (aliased)
    __shared__ __align__(16) char lds[33792];

    const int l = lmin + blockIdx.z;
    const int t = d - l;
    const size_t slab = (size_t)BSZ * HSZ;
    auto Hb = [&](int par, int ll, int hilo) {
        return hbuf + (((size_t)par * 3 + ll) * 2 + hilo) * slab;
    };

    const __hip_bfloat16* Wth = (l == 0) ? W0h : (l == 1) ? W1h : W2h;
    const __hip_bfloat16* Wtl = (l == 0) ? W0l : (l == 1) ? W1l : W2l;
    const float* bias = (l == 0) ? b0 : (l == 1) ? b1 : b2;
    const int Kx   = (l == 0) ? INSZ : HSZ;
    const int KCax = (l == 0) ? 8 : 64;   // kcs per panel in the x-source slab
    const int Ktot = Kx + HSZ;
    const int KCt  = Ktot >> 3;
    const int nkx  = Kx >> 6;     // ksteps in x phase (1 or 8)
    const int nkt  = Ktot >> 6;   // total ksteps (9 or 16)
    const int cur = t & 1, prv = cur ^ 1;
    const __hip_bfloat16* Axh = (l == 0) ? xth + (size_t)t * BSZ * INSZ : Hb(cur, l - 1, 0);
    const __hip_bfloat16* Axl = (l == 0) ? xtl + (size_t)t * BSZ * INSZ : Hb(cur, l - 1, 1);
    const __hip_bfloat16* Ahh = Hb(prv, l, 0);
    const __hip_bfloat16* Ahl = Hb(prv, l, 1);
    float* C = Cbuf + (size_t)l * slab;
    __hip_bfloat16* hhi = Hb(cur, l, 0);
    __hip_bfloat16* hlo = Hb(cur, l, 1);

    // XCD-aware bijective swizzle within the 256-block z-slice (256 % 8 == 0).
    const int bid = blockIdx.x + (blockIdx.y << 4);
    const int swz = (bid & 7) * 32 + (bid >> 3);
    const int m0 = (swz & 15) * 64;
    const int n0 = (swz >> 4) * 128;
    const int p  = swz & 15;    // A row-panel
    const int np = swz >> 4;    // W col-panel

    const int tid = threadIdx.x;
    const int lane = tid & 63;
    const int wv = tid >> 6;
    const int lrow32 = lane & 31;
    const int lk2 = lane >> 5;

    // A source byte bases (panel-resolved)
    const char* bAxh = (const char*)Axh + (size_t)p * KCax * 1024;
    const char* bAxl = (const char*)Axl + (size_t)p * KCax * 1024;
    const char* bAhh = (const char*)Ahh + (size_t)p * 64 * 1024;
    const char* bAhl = (const char*)Ahl + (size_t)p * 64 * 1024;
    // W byte bases (panel-resolved)
    const char* bWh = (const char*)Wth + (size_t)np * KCt * 2048;
    const char* bWl = (const char*)Wtl + (size_t)np * KCt * 2048;

    // per-lane offsets: wave owns cols [wv*32, wv*32+32) of the 128-col block
    const int boff = (wv * 32 + lrow32) * 16;   // + kc*2048
    const int aoff = lrow32 * 16;               // + kc*1024 (+512 for rows 32-63)

    f32x16 acc0, acc1;
#pragma unroll
    for (int r = 0; r < 16; ++r) { acc0[r] = 0.0f; acc1[r] = 0.0f; }

    // stage A kstep ks into buf[ks&1]: 16 x 1KB segments, 4 per wave
    auto stage = [&](int ks) {
        const char *sh, *sl;
        int kc0;
        if (ks < nkx) { sh = bAxh; sl = bAxl; kc0 = ks * 8; }
        else          { sh = bAhh; sl = bAhl; kc0 = (ks - nkx) * 8; }
        char* dst = lds + (ks & 1) * 16384;
#pragma unroll
        for (int i = 0; i < 2; ++i) {
            int kc = wv * 2 + i;
            size_t so = (size_t)(kc0 + kc) * 1024 + lane * 16;
            GLDS16(sh + so, dst + kc * 1024);
            GLDS16(sl + so, dst + 8192 + kc * 1024);
        }
    };

    bf16x8 bA[8], bB[8];   // [0..3]=hi per ksub, [4..7]=lo per ksub

#define LOADB(SET, KS)                                                      \
    { const char* wb_ = bWh + (size_t)(KS) * 16384;                         \
      const char* wl_ = bWl + (size_t)(KS) * 16384;                         \
      _Pragma("unroll")                                                     \
      for (int s_ = 0; s_ < 4; ++s_) {                                      \
          int ko_ = (s_ * 2 + lk2) * 2048 + boff;                           \
          SET[s_]     = *(const bf16x8*)(wb_ + ko_);                        \
          SET[s_ + 4] = *(const bf16x8*)(wl_ + ko_);                        \
      } }

#define COMPUTE(SET, KS)                                                    \
    { char* buf_ = lds + ((KS) & 1) * 16384;                                \
      __builtin_amdgcn_s_setprio(1);                                        \
      _Pragma("unroll")                                                     \
      for (int s_ = 0; s_ < 4; ++s_) {                                      \
          int ao_ = (s_ * 2 + lk2) * 1024 + aoff;                           \
          bf16x8 ah0 = *(const bf16x8*)(buf_ + ao_);                        \
          bf16x8 ah1 = *(const bf16x8*)(buf_ + ao_ + 512);                  \
          bf16x8 al0 = *(const bf16x8*)(buf_ + 8192 + ao_);                 \
          bf16x8 al1 = *(const bf16x8*)(buf_ + 8192 + ao_ + 512);           \
          acc0 = __builtin_amdgcn_mfma_f32_32x32x16_bf16(ah0, SET[s_], acc0, 0, 0, 0);     \
          acc1 = __builtin_amdgcn_mfma_f32_32x32x16_bf16(ah1, SET[s_], acc1, 0, 0, 0);     \
          acc0 = __builtin_amdgcn_mfma_f32_32x32x16_bf16(al0, SET[s_], acc0, 0, 0, 0);     \
          acc1 = __builtin_amdgcn_mfma_f32_32x32x16_bf16(al1, SET[s_], acc1, 0, 0, 0);     \
          acc0 = __builtin_amdgcn_mfma_f32_32x32x16_bf16(ah0, SET[s_ + 4], acc0, 0, 0, 0); \
          acc1 = __builtin_amdgcn_mfma_f32_32x32x16_bf16(ah1, SET[s_ + 4], acc1, 0, 0, 0); \
      }                                                                     \
      __builtin_amdgcn_s_setprio(0); }

    // prologue: B[0] + A[0] in flight; barrier drains both (one exposed RT)
    LOADB(bA, 0)
    stage(0);
    __syncthreads();

#pragma unroll 1
    for (int ks = 0; ks < nkt; ) {
        // even step: consume bA; prefetch B[ks+1] into bB
        if (ks + 1 < nkt) { LOADB(bB, ks + 1) stage(ks + 1); }
        __builtin_amdgcn_sched_barrier(0);  // loads issued before MFMA cluster
        COMPUTE(bA, ks)
        __syncthreads();
        ++ks;
        if (ks == nkt) break;
        // odd step: consume bB; prefetch B[ks+1] into bA
        if (ks + 1 < nkt) { LOADB(bA, ks + 1) stage(ks + 1); }
        __builtin_amdgcn_sched_barrier(0);
        COMPUTE(bB, ks)
        __syncthreads();
        ++ks;
    }
#undef LOADB
#undef COMPUTE

    // ---- epilogue: acc -> LDS [64][132] f32, then fused cell update ----
    // (last K-loop barrier already synced; gt aliases the A bufs)
    float* gt = (float*)lds;
#pragma unroll
    for (int rg = 0; rg < 16; ++rg) {
        int row = (rg & 3) + 8 * (rg >> 2) + 4 * lk2;
        gt[row * 132 + wv * 32 + lrow32] = acc0[rg];
        gt[(row + 32) * 132 + wv * 32 + lrow32] = acc1[rg];
    }
    __syncthreads();

    const int n_l = tid & 31;
    const int rb2 = (tid >> 5) * 8;
    const int n_g = (n0 >> 2) + n_l;  // global hidden unit
    const int kc_h = n_g >> 3, e_h = n_g & 7;
    const float bf = bias[n_g], bi = bias[HSZ + n_g];
    const float bc = bias[2 * HSZ + n_g], bo = bias[3 * HSZ + n_g];
#pragma unroll
    for (int r = 0; r < 8; ++r) {
        int row = rb2 + r;
        int rg = m0 + row;
        float4 g4 = *(const float4*)&gt[row * 132 + n_l * 4];  // f,i,c,o
        float f = sigmf(g4.x + bf);
        float i_ = sigmf(g4.y + bi);
        float c_ = tanhf_(g4.z + bc);
        float o_ = sigmf(g4.w + bo);
        size_t cidx = (size_t)rg * HSZ + n_g;
        float Cn = f * C[cidx] + i_ * c_;
        C[cidx] = Cn;
        float hv = o_ * tanhf_(Cn);
        __hip_bfloat16 hh = __float2bfloat16(hv);
        size_t hidx = (((size_t)(rg >> 6) * 64 + kc_h) * 64 + (rg & 63)) * 8 + e_h;
        hhi[hidx] = hh;
        hlo[hidx] = __float2bfloat16(hv - __bfloat162float(hh));
    }
}

// x[B][T][64] f32 -> xt_pk[t][p][kc][r][e] bf16 hi/lo
__global__ __launch_bounds__(256) void convert_x(const float* __restrict__ x,
                                                 __hip_bfloat16* __restrict__ xh,
                                                 __hip_bfloat16* __restrict__ xl)
{
    int gid = blockIdx.x * 256 + threadIdx.x;  // T*16*64*8
    int kc = gid & 7;
    int rem = gid >> 3;
    int r = rem & 63; rem >>= 6;
    int pp = rem & 15;
    int t = rem >> 4;
    int b = pp * 64 + r;
    const float* src = x + ((size_t)b * TSZ + t) * INSZ + kc * 8;
    short hi8[8], lo8[8];
#pragma unroll
    for (int e = 0; e < 8; ++e) {
        float v = src[e];
        __hip_bfloat16 h = __float2bfloat16(v);
        hi8[e] = *(short*)&h;
        __hip_bfloat16 lo = __float2bfloat16(v - __bfloat162float(h));
        lo8[e] = *(short*)&lo;
    }
    size_t o = ((((size_t)t * 16 + pp) * 8 + kc) * 64 + r) * 8;
    *(bf16x8*)((__hip_bfloat16*)xh + o) = *(bf16x8*)hi8;
    *(bf16x8*)((__hip_bfloat16*)xl + o) = *(bf16x8*)lo8;
}

// W[k][gate*512+n] f32 (Wx then Wh stacked in k) -> W_pk[np][kc][c][e] bf16 hi/lo
// grid (Ktot/64, 16): block = (kt, np), 64 k x 128 col'
__global__ __launch_bounds__(256) void convert_w(
    const float* __restrict__ Wx, const float* __restrict__ Wh, int Kx, int Ktot,
    __hip_bfloat16* __restrict__ outh, __hip_bfloat16* __restrict__ outl)
{
    __shared__ float tile[64][129];
    const int kt = blockIdx.x, np = blockIdx.y;
    const int k0 = kt * 64;
    const float* src;
    int krel;
    if (k0 < Kx) { src = Wx; krel = k0; } else { src = Wh; krel = k0 - Kx; }
#pragma unroll
    for (int i = 0; i < 32; ++i) {
        int idx = threadIdx.x + i * 256;
        int k_l = idx >> 7, gate = (idx >> 5) & 3, n_l = idx & 31;
        tile[k_l][n_l * 4 + gate] = src[(size_t)(krel + k_l) * GSZ + gate * HSZ + np * 32 + n_l];
    }
    __syncthreads();
    const size_t obase = ((size_t)np * (Ktot >> 3) + kt * 8) * 1024;
#pragma unroll
    for (int i = 0; i < 32; ++i) {
        int idx = threadIdx.x + i * 256;
        int kcl = idx >> 10, c = (idx >> 3) & 127, e = idx & 7;
        float v = tile[kcl * 8 + e][c];
        __hip_bfloat16 h = __float2bfloat16(v);
        outh[obase + idx] = h;
        outl[obase + idx] = __float2bfloat16(v - __bfloat162float(h));
    }
}

// out[b] = sum_n (hh+hl)[b][n]*w[n] + bias, h in pk layout
__global__ __launch_bounds__(256) void fc_kernel(
    const __hip_bfloat16* __restrict__ hh, const __hip_bfloat16* __restrict__ hl,
    const float* __restrict__ w, const float* __restrict__ b, float* __restrict__ out)
{
    int wave = (blockIdx.x * 256 + threadIdx.x) >> 6;  // batch row
    int lane = threadIdx.x & 63;
    if (wave >= BSZ) return;
    int pp = wave >> 6, r = wave & 63;
    size_t o = (((size_t)pp * 64 + lane) * 64 + r) * 8;  // kc = lane
    bf16x8 vh = *(const bf16x8*)(hh + o);
    bf16x8 vl = *(const bf16x8*)(hl + o);
    float s = 0.0f;
#pragma unroll
    for (int e = 0; e < 8; ++e) {
        ushort uh = (ushort)vh[e], ul = (ushort)vl[e];
        __hip_bfloat16 bh = *(__hip_bfloat16*)&uh;
        __hip_bfloat16 bl = *(__hip_bfloat16*)&ul;
        s += (__bfloat162float(bh) + __bfloat162float(bl)) * w[lane * 8 + e];
    }
#pragma unroll
    for (int off = 32; off; off >>= 1) s += __shfl_down(s, off);
    if (lane == 0) out[wave] = s + b[0];
}

extern "C" void kernel_launch(void* const* d_in, const int* in_sizes, int n_in,
                              void* d_out, int out_size, void* d_ws, size_t ws_size,
                              hipStream_t stream) {
    const float* x   = (const float*)d_in[0];
    const float* Wx0 = (const float*)d_in[1];
    const float* Wh0 = (const float*)d_in[2];
    const float* b0  = (const float*)d_in[3];
    const float* Wx1 = (const float*)d_in[4];
    const float* Wh1 = (const float*)d_in[5];
    const float* b1  = (const float*)d_in[6];
    const float* Wx2 = (const float*)d_in[7];
    const float* Wh2 = (const float*)d_in[8];
    const float* b2  = (const float*)d_in[9];
    const float* fcw = (const float*)d_in[10];
    const float* fcb = (const float*)d_in[11];

    char* p = (char*)d_ws;
    const size_t hslab = (size_t)BSZ * HSZ * sizeof(__hip_bfloat16);  // 1 MiB
    __hip_bfloat16* hbuf = (__hip_bfloat16*)p;  // [par][layer][hi/lo] 12 slabs
    p += 12 * hslab;
    float* Cbuf = (float*)p;  // [3][B][H] f32
    p += 3 * (size_t)BSZ * HSZ * sizeof(float);
    const size_t zero_bytes = (size_t)(p - (char*)d_ws);

    const size_t xslab = (size_t)TSZ * BSZ * INSZ * sizeof(__hip_bfloat16);
    __hip_bfloat16* xth = (__hip_bfloat16*)p; p += xslab;
    __hip_bfloat16* xtl = (__hip_bfloat16*)p; p += xslab;

    const int K0 = INSZ + HSZ;   // 576
    const int K12 = 2 * HSZ;     // 1024
    const size_t w0s = (size_t)GSZ * K0 * sizeof(__hip_bfloat16);
    const size_t w12s = (size_t)GSZ * K12 * sizeof(__hip_bfloat16);
    __hip_bfloat16* w0h = (__hip_bfloat16*)p; p += w0s;
    __hip_bfloat16* w0l = (__hip_bfloat16*)p; p += w0s;
    __hip_bfloat16* w1h = (__hip_bfloat16*)p; p += w12s;
    __hip_bfloat16* w1l = (__hip_bfloat16*)p; p += w12s;
    __hip_bfloat16* w2h = (__hip_bfloat16*)p; p += w12s;
    __hip_bfloat16* w2l = (__hip_bfloat16*)p; p += w12s;

    hipMemsetAsync(d_ws, 0, zero_bytes, stream);

    convert_x<<<dim3(TSZ * BSZ * 8 / 256), dim3(256), 0, stream>>>(x, xth, xtl);
    convert_w<<<dim3(K0 / 64, 16), dim3(256), 0, stream>>>(Wx0, Wh0, INSZ, K0, w0h, w0l);
    convert_w<<<dim3(K12 / 64, 16), dim3(256), 0, stream>>>(Wx1, Wh1, HSZ, K12, w1h, w1l);
    convert_w<<<dim3(K12 / 64, 16), dim3(256), 0, stream>>>(Wx2, Wh2, HSZ, K12, w2h, w2l);

    // diagonal wavefront: d = t + l, cells (t,l) with t+l == d are independent
    for (int dgn = 0; dgn < TSZ + 2; ++dgn) {
        int lmin = (dgn - (TSZ - 1)) > 0 ? (dgn - (TSZ - 1)) : 0;
        int lmax = dgn < 2 ? dgn : 2;
        int ncells = lmax - lmin + 1;
        lstm_diag<<<dim3(16, 16, ncells), dim3(256), 0, stream>>>(
            xth, xtl, hbuf, Cbuf,
            w0h, w0l, w1h, w1l, w2h, w2l,
            b0, b1, b2, dgn, lmin);
    }

    // h of layer 2 at t=47 lives at parity 47&1 = 1
    __hip_bfloat16* h2h = hbuf + (((size_t)1 * 3 + 2) * 2 + 0) * BSZ * HSZ;
    __hip_bfloat16* h2l = hbuf + (((size_t)1 * 3 + 2) * 2 + 1) * BSZ * HSZ;
    fc_kernel<<<dim3(BSZ / 4), dim3(256), 0, stream>>>(h2h, h2l, fcw, fcb, (float*)d_out);
}